// Round 2
// baseline (1396.912 us; speedup 1.0000x reference)
//
#include <hip/hip_runtime.h>

#define SEQ 365
#define BS  2048
#define HS  64
#define IND 32
#define XXC 5

__device__ __forceinline__ float rcp_(float x) { return __builtin_amdgcn_rcpf(x); }
__device__ __forceinline__ float sig_(float x) { return rcp_(1.0f + __expf(-x)); }
__device__ __forceinline__ float tanh_(float x) { return 1.0f - 2.0f * rcp_(1.0f + __expf(2.0f * x)); }
__device__ __forceinline__ float bcast_(float v, int lane) {
    return __int_as_float(__builtin_amdgcn_readlane(__float_as_int(v), lane));
}

// One wave = TWO batch samples sharing the register-resident weights.
// Lane j owns output columns (j, 64+j, 128+j) for both samples. The two
// samples' FMA/transcendental chains are independent -> latency hiding at
// 1 wave/SIMD occupancy (weights ~306 regs force 1 wave/SIMD; 1024 waves
// = exactly 1 per SIMD across the chip, single pass).
__global__ __launch_bounds__(64, 1)
void tlstm_kernel(const float* __restrict__ x_for_h,
                  const float* __restrict__ x_for_x,
                  const float* __restrict__ td_in,
                  const float* __restrict__ Wx,    // [32][192]
                  const float* __restrict__ Wxm,   // [5][128]
                  const float* __restrict__ Wh,    // [64][192]
                  const float* __restrict__ Wt1,   // [64]
                  const float* __restrict__ Wt,    // [128]
                  const float* __restrict__ bias,  // [320]
                  float* __restrict__ out)
{
    const int b0 = blockIdx.x * 2;
    const int j = threadIdx.x;

    // ---- register-resident weights (persist across all 365 steps) ----
    float wx0[IND], wxc[IND], wxo[IND];
#pragma unroll
    for (int k = 0; k < IND; ++k) {
        wx0[k] = Wx[k * 192 + j];
        wxc[k] = Wx[k * 192 + 64 + j];
        wxo[k] = Wx[k * 192 + 128 + j];
    }
    float wh0[HS], whc[HS], who[HS];
#pragma unroll
    for (int k = 0; k < HS; ++k) {
        wh0[k] = Wh[k * 192 + j];
        whc[k] = Wh[k * 192 + 64 + j];
        who[k] = Wh[k * 192 + 128 + j];
    }
    float wm1[XXC], wm2[XXC];
#pragma unroll
    for (int k = 0; k < XXC; ++k) {
        wm1[k] = Wxm[k * 128 + j];
        wm2[k] = Wxm[k * 128 + 64 + j];
    }
    const float wt1j = fminf(Wt1[j], 0.0f);  // torch clamps max=0 (idempotent)
    const float wtA  = Wt[j];
    const float wtB  = Wt[64 + j];
    const float b0i = bias[j], b1i = bias[64 + j], b2i = bias[128 + j];
    const float b3i = bias[192 + j], b4i = bias[256 + j];

    float h[2] = {0.0f, 0.0f}, c[2] = {0.0f, 0.0f};

    const float* xh[2];
    const float* xx[2];
    const float* tdp[2];
    float* outp[2];
#pragma unroll
    for (int s = 0; s < 2; ++s) {
        const int b = b0 + s;
        xh[s]   = x_for_h + (size_t)b * SEQ * IND;
        xx[s]   = x_for_x + (size_t)b * SEQ * XXC;
        tdp[s]  = td_in + (size_t)b * SEQ;
        outp[s] = out + (size_t)b * SEQ * HS + j;
    }

    for (int t = 0; t < SEQ; ++t) {
        float acc_i[2] = {b0i, b0i};
        float acc_c[2] = {b3i, b3i};
        float acc_o[2] = {b4i, b4i};

        // x @ Wx : x values are wave-uniform -> scalar loads; two samples
        // give two independent FMA chains per weight.
#pragma unroll
        for (int k = 0; k < IND; ++k) {
            const float xv0 = xh[0][k];
            const float xv1 = xh[1][k];
            acc_i[0] = fmaf(xv0, wx0[k], acc_i[0]);
            acc_i[1] = fmaf(xv1, wx0[k], acc_i[1]);
            acc_c[0] = fmaf(xv0, wxc[k], acc_c[0]);
            acc_c[1] = fmaf(xv1, wxc[k], acc_c[1]);
            acc_o[0] = fmaf(xv0, wxo[k], acc_o[0]);
            acc_o[1] = fmaf(xv1, wxo[k], acc_o[1]);
        }
        // h @ Wh : broadcast via readlane (SGPR), independent per sample
#pragma unroll
        for (int k = 0; k < HS; ++k) {
            const float hk0 = bcast_(h[0], k);
            const float hk1 = bcast_(h[1], k);
            acc_i[0] = fmaf(hk0, wh0[k], acc_i[0]);
            acc_i[1] = fmaf(hk1, wh0[k], acc_i[1]);
            acc_c[0] = fmaf(hk0, whc[k], acc_c[0]);
            acc_c[1] = fmaf(hk1, whc[k], acc_c[1]);
            acc_o[0] = fmaf(hk0, who[k], acc_o[0]);
            acc_o[1] = fmaf(hk1, who[k], acc_o[1]);
        }
        // xx @ Wxm
        float am1[2] = {b1i, b1i};
        float am2[2] = {b2i, b2i};
#pragma unroll
        for (int k = 0; k < XXC; ++k) {
            const float xv0 = xx[0][k];
            const float xv1 = xx[1][k];
            am1[0] = fmaf(xv0, wm1[k], am1[0]);
            am1[1] = fmaf(xv1, wm1[k], am1[1]);
            am2[0] = fmaf(xv0, wm2[k], am2[0]);
            am2[1] = fmaf(xv1, wm2[k], am2[1]);
        }

#pragma unroll
        for (int s = 0; s < 2; ++s) {
            const float td = tdp[s][t];
            const float i_t  = sig_(acc_i[s]);
            const float t1   = sig_(am1[s] + tanh_(td * wt1j));
            const float t2   = sig_(am2[s] + tanh_(td * wtA));
            const float capp = tanh_(acc_c[s]);
            const float it1  = i_t * t1;
            // c_tilde = sigmoid(c + i*t1*(capp - c))
            const float ctl  = sig_(fmaf(it1, capp - c[s], c[s]));
            // c_new = sigmoid(c + i*(t2*capp - c))
            const float cn   = sig_(fmaf(i_t, fmaf(t2, capp, -c[s]), c[s]));
            const float o_t  = sig_(fmaf(td, wtB, acc_o[s]));
            const float hn   = o_t + tanh_(ctl);

            outp[s][(size_t)t * HS] = hn;  // coalesced: lane j -> element j
            h[s] = hn;
            c[s] = cn;
        }
        xh[0] += IND; xh[1] += IND;
        xx[0] += XXC; xx[1] += XXC;
    }

    // finals: out = [hidden_seq | h_T | c_T]
    float* hT = out + (size_t)BS * SEQ * HS;
    float* cT = hT + (size_t)BS * HS;
#pragma unroll
    for (int s = 0; s < 2; ++s) {
        hT[(size_t)(b0 + s) * HS + j] = h[s];
        cT[(size_t)(b0 + s) * HS + j] = c[s];
    }
}

extern "C" void kernel_launch(void* const* d_in, const int* in_sizes, int n_in,
                              void* d_out, int out_size, void* d_ws, size_t ws_size,
                              hipStream_t stream)
{
    const float* x_for_h = (const float*)d_in[0];
    const float* x_for_x = (const float*)d_in[1];
    const float* TimeDiff = (const float*)d_in[2];
    const float* weights_x = (const float*)d_in[3];
    const float* weights_x_maintained = (const float*)d_in[4];
    const float* weights_h = (const float*)d_in[5];
    const float* weights_t1 = (const float*)d_in[6];
    const float* weights_t = (const float*)d_in[7];
    const float* bias = (const float*)d_in[8];
    float* out = (float*)d_out;

    tlstm_kernel<<<BS / 2, 64, 0, stream>>>(x_for_h, x_for_x, TimeDiff,
                                            weights_x, weights_x_maintained, weights_h,
                                            weights_t1, weights_t, bias, out);
}

// Round 3
// 1016.938 us; speedup vs baseline: 1.3736x; 1.3736x over previous
//
#include <hip/hip_runtime.h>

#define SEQ 365
#define BS  2048
#define HS  64
#define IND 32
#define XXC 5
#define NROWS (BS * SEQ)          // 747520
#define PRE_STRIDE 192
#define WS_NEEDED ((size_t)NROWS * PRE_STRIDE * sizeof(float))  // ~574 MB

__device__ __forceinline__ float rcp_(float x) { return __builtin_amdgcn_rcpf(x); }
__device__ __forceinline__ float sig_(float x) { return rcp_(1.0f + __expf(-x)); }
__device__ __forceinline__ float tanh_(float x) { return 1.0f - 2.0f * rcp_(1.0f + __expf(2.0f * x)); }
__device__ __forceinline__ float bcast_(float v, int lane) {
    return __int_as_float(__builtin_amdgcn_readlane(__float_as_int(v), lane));
}

// ---------------- Phase 1: pregates (no recurrence, pure batch) ----------
// pre[r][0:64]   = bias0 + x_r @ Wx[:, 0:64]
// pre[r][64:128] = bias3 + x_r @ Wx[:, 64:128]
// pre[r][128:192]= bias4 + td_r*wtB + x_r @ Wx[:, 128:192]
#define RPW 32  // rows per block (64-thread block = 1 wave)
__global__ __launch_bounds__(64, 2)
void pregate_kernel(const float* __restrict__ x_for_h,
                    const float* __restrict__ td_in,
                    const float* __restrict__ Wx,    // [32][192]
                    const float* __restrict__ Wt,    // [128]
                    const float* __restrict__ bias,  // [320]
                    float* __restrict__ pre)
{
    const int j = threadIdx.x;
    float wx0[IND], wxc[IND], wxo[IND];
#pragma unroll
    for (int k = 0; k < IND; ++k) {
        wx0[k] = Wx[k * 192 + j];
        wxc[k] = Wx[k * 192 + 64 + j];
        wxo[k] = Wx[k * 192 + 128 + j];
    }
    const float wtB = Wt[64 + j];
    const float b0i = bias[j], b3i = bias[192 + j], b4i = bias[256 + j];

    const int r0 = blockIdx.x * RPW;
    for (int r = r0; r < r0 + RPW; ++r) {
        const float* xr = x_for_h + (size_t)r * IND;  // wave-uniform -> s_load
        float ai = b0i, ac = b3i;
        float ao = fmaf(td_in[r], wtB, b4i);
#pragma unroll
        for (int k = 0; k < IND; ++k) {
            const float xv = xr[k];
            ai = fmaf(xv, wx0[k], ai);
            ac = fmaf(xv, wxc[k], ac);
            ao = fmaf(xv, wxo[k], ao);
        }
        float* p = pre + (size_t)r * PRE_STRIDE;
        p[j] = ai;
        p[64 + j] = ac;
        p[128 + j] = ao;
    }
}

// ---------------- Phase 2: recurrence only -------------------------------
// Register set ~235 floats (Wh 192 + Wm 10 + scalars) -> fits 256 VGPR ->
// 2 waves/SIMD: all 2048 waves resident in one pass, cross-wave hiding.
__global__ __launch_bounds__(64, 2)
void recur_kernel(const float* __restrict__ pre,
                  const float* __restrict__ x_for_x,
                  const float* __restrict__ td_in,
                  const float* __restrict__ Wxm,   // [5][128]
                  const float* __restrict__ Wh,    // [64][192]
                  const float* __restrict__ Wt1,   // [64]
                  const float* __restrict__ Wt,    // [128]
                  const float* __restrict__ bias,  // [320]
                  float* __restrict__ out)
{
    const int b = blockIdx.x;
    const int j = threadIdx.x;

    float wh0[HS], whc[HS], who[HS];
#pragma unroll
    for (int k = 0; k < HS; ++k) {
        wh0[k] = Wh[k * 192 + j];
        whc[k] = Wh[k * 192 + 64 + j];
        who[k] = Wh[k * 192 + 128 + j];
    }
    float wm1[XXC], wm2[XXC];
#pragma unroll
    for (int k = 0; k < XXC; ++k) {
        wm1[k] = Wxm[k * 128 + j];
        wm2[k] = Wxm[k * 128 + 64 + j];
    }
    const float wt1j = fminf(Wt1[j], 0.0f);
    const float wtA  = Wt[j];
    const float b1i = bias[64 + j], b2i = bias[128 + j];

    float h = 0.0f, c = 0.0f;

    const float* prep = pre + (size_t)b * SEQ * PRE_STRIDE;
    const float* xx   = x_for_x + (size_t)b * SEQ * XXC;   // wave-uniform
    const float* tdp  = td_in + (size_t)b * SEQ;           // wave-uniform
    float* outp = out + (size_t)b * SEQ * HS + j;

    for (int t = 0; t < SEQ; ++t) {
        // issue pre-loads first; the h-FMA chain below hides their latency
        const float pi = prep[j];
        const float pc = prep[64 + j];
        const float po = prep[128 + j];

        float ai = 0.0f, ac = 0.0f, ao = 0.0f;
#pragma unroll
        for (int k = 0; k < HS; ++k) {
            const float hk = bcast_(h, k);
            ai = fmaf(hk, wh0[k], ai);
            ac = fmaf(hk, whc[k], ac);
            ao = fmaf(hk, who[k], ao);
        }
        float am1 = b1i, am2 = b2i;
#pragma unroll
        for (int k = 0; k < XXC; ++k) {
            const float xv = xx[k];
            am1 = fmaf(xv, wm1[k], am1);
            am2 = fmaf(xv, wm2[k], am2);
        }
        const float td = tdp[t];

        const float i_t  = sig_(ai + pi);
        const float t1   = sig_(am1 + tanh_(td * wt1j));
        const float t2   = sig_(am2 + tanh_(td * wtA));
        const float capp = tanh_(ac + pc);
        const float it1  = i_t * t1;
        const float ctl  = sig_(fmaf(it1, capp - c, c));           // sigmoid(c + i*t1*(capp-c))
        const float cn   = sig_(fmaf(i_t, fmaf(t2, capp, -c), c)); // sigmoid(c + i*(t2*capp-c))
        const float o_t  = sig_(ao + po);                          // td*wtB folded in phase 1
        const float hn   = o_t + tanh_(ctl);

        outp[(size_t)t * HS] = hn;
        h = hn;
        c = cn;
        prep += PRE_STRIDE;
        xx += XXC;
    }

    float* hT = out + (size_t)BS * SEQ * HS;
    float* cT = hT + (size_t)BS * HS;
    hT[(size_t)b * HS + j] = h;
    cT[(size_t)b * HS + j] = c;
}

// ---------------- Fallback: proven monolithic R1 kernel ------------------
__global__ __launch_bounds__(64, 1)
void tlstm_mono(const float* __restrict__ x_for_h,
                const float* __restrict__ x_for_x,
                const float* __restrict__ td_in,
                const float* __restrict__ Wx,
                const float* __restrict__ Wxm,
                const float* __restrict__ Wh,
                const float* __restrict__ Wt1,
                const float* __restrict__ Wt,
                const float* __restrict__ bias,
                float* __restrict__ out)
{
    const int b = blockIdx.x;
    const int j = threadIdx.x;
    float wx0[IND], wxc[IND], wxo[IND];
#pragma unroll
    for (int k = 0; k < IND; ++k) {
        wx0[k] = Wx[k * 192 + j];
        wxc[k] = Wx[k * 192 + 64 + j];
        wxo[k] = Wx[k * 192 + 128 + j];
    }
    float wh0[HS], whc[HS], who[HS];
#pragma unroll
    for (int k = 0; k < HS; ++k) {
        wh0[k] = Wh[k * 192 + j];
        whc[k] = Wh[k * 192 + 64 + j];
        who[k] = Wh[k * 192 + 128 + j];
    }
    float wm1[XXC], wm2[XXC];
#pragma unroll
    for (int k = 0; k < XXC; ++k) {
        wm1[k] = Wxm[k * 128 + j];
        wm2[k] = Wxm[k * 128 + 64 + j];
    }
    const float wt1j = fminf(Wt1[j], 0.0f);
    const float wtA = Wt[j], wtB = Wt[64 + j];
    const float b0i = bias[j], b1i = bias[64 + j], b2i = bias[128 + j];
    const float b3i = bias[192 + j], b4i = bias[256 + j];

    float h = 0.0f, c = 0.0f;
    const float* xh  = x_for_h + (size_t)b * SEQ * IND;
    const float* xx  = x_for_x + (size_t)b * SEQ * XXC;
    const float* tdp = td_in + (size_t)b * SEQ;
    float* outp = out + (size_t)b * SEQ * HS + j;

    for (int t = 0; t < SEQ; ++t) {
        float ai = b0i, ac = b3i, ao = b4i;
#pragma unroll
        for (int k = 0; k < IND; ++k) {
            const float xv = xh[k];
            ai = fmaf(xv, wx0[k], ai);
            ac = fmaf(xv, wxc[k], ac);
            ao = fmaf(xv, wxo[k], ao);
        }
#pragma unroll
        for (int k = 0; k < HS; ++k) {
            const float hk = bcast_(h, k);
            ai = fmaf(hk, wh0[k], ai);
            ac = fmaf(hk, whc[k], ac);
            ao = fmaf(hk, who[k], ao);
        }
        float am1 = b1i, am2 = b2i;
#pragma unroll
        for (int k = 0; k < XXC; ++k) {
            const float xv = xx[k];
            am1 = fmaf(xv, wm1[k], am1);
            am2 = fmaf(xv, wm2[k], am2);
        }
        const float td = tdp[t];
        const float i_t  = sig_(ai);
        const float t1   = sig_(am1 + tanh_(td * wt1j));
        const float t2   = sig_(am2 + tanh_(td * wtA));
        const float capp = tanh_(ac);
        const float it1  = i_t * t1;
        const float ctl  = sig_(fmaf(it1, capp - c, c));
        const float cn   = sig_(fmaf(i_t, fmaf(t2, capp, -c), c));
        const float o_t  = sig_(fmaf(td, wtB, ao));
        const float hn   = o_t + tanh_(ctl);
        outp[(size_t)t * HS] = hn;
        h = hn; c = cn;
        xh += IND; xx += XXC;
    }
    float* hT = out + (size_t)BS * SEQ * HS;
    float* cT = hT + (size_t)BS * HS;
    hT[(size_t)b * HS + j] = h;
    cT[(size_t)b * HS + j] = c;
}

extern "C" void kernel_launch(void* const* d_in, const int* in_sizes, int n_in,
                              void* d_out, int out_size, void* d_ws, size_t ws_size,
                              hipStream_t stream)
{
    const float* x_for_h = (const float*)d_in[0];
    const float* x_for_x = (const float*)d_in[1];
    const float* TimeDiff = (const float*)d_in[2];
    const float* weights_x = (const float*)d_in[3];
    const float* weights_x_maintained = (const float*)d_in[4];
    const float* weights_h = (const float*)d_in[5];
    const float* weights_t1 = (const float*)d_in[6];
    const float* weights_t = (const float*)d_in[7];
    const float* bias = (const float*)d_in[8];
    float* out = (float*)d_out;

    if (ws_size >= WS_NEEDED) {
        float* pre = (float*)d_ws;
        pregate_kernel<<<NROWS / RPW, 64, 0, stream>>>(x_for_h, TimeDiff,
                                                       weights_x, weights_t, bias, pre);
        recur_kernel<<<BS, 64, 0, stream>>>(pre, x_for_x, TimeDiff,
                                            weights_x_maintained, weights_h,
                                            weights_t1, weights_t, bias, out);
    } else {
        tlstm_mono<<<BS, 64, 0, stream>>>(x_for_h, x_for_x, TimeDiff,
                                          weights_x, weights_x_maintained, weights_h,
                                          weights_t1, weights_t, bias, out);
    }
}